// Round 7
// baseline (2918.171 us; speedup 1.0000x reference)
//
#include <hip/hip_runtime.h>
#include <cstdint>
#include <cstddef>

#define NN 32
#define NODE_ELEMS 1605632  // 8*56*56*64 (NHWC workspace layout)

typedef unsigned __int128 u128;

// ---------------- host: replicate np.random.default_rng(0).random((32,32)) < 0.25 ----
static void compute_adj(bool adj[NN][NN]) {
  uint32_t pool[4];
  uint32_t hc = 0x43b0d7e5u;
  auto hashmix = [&hc](uint32_t v) -> uint32_t {
    v ^= hc; hc *= 0x931e8875u; v *= hc; v ^= v >> 16; return v;
  };
  auto mix = [](uint32_t x, uint32_t y) -> uint32_t {
    uint32_t r = x * 0xca01f9ddu - y * 0x4973f715u; r ^= r >> 16; return r;
  };
  for (int i = 0; i < 4; i++) pool[i] = hashmix(0u);
  for (int s = 0; s < 4; s++)
    for (int d = 0; d < 4; d++)
      if (s != d) pool[d] = mix(pool[d], hashmix(pool[s]));
  uint32_t hb = 0x8b51f9ddu;
  uint32_t w[8];
  for (int k = 0; k < 8; k++) {
    uint32_t v = pool[k & 3];
    v ^= hb; hb *= 0x58f38dedu; v *= hb; v ^= v >> 16;
    w[k] = v;
  }
  uint64_t s64[4];
  for (int j = 0; j < 4; j++) s64[j] = (uint64_t)w[2 * j] | ((uint64_t)w[2 * j + 1] << 32);
  u128 initstate = ((u128)s64[0] << 64) | s64[1];
  u128 initseq   = ((u128)s64[2] << 64) | s64[3];
  const u128 MULT = ((u128)0x2360ED051FC65DA4ULL << 64) | 0x4385DF649FCCF645ULL;
  u128 state = 0;
  u128 inc = (initseq << 1) | 1;
  state = state * MULT + inc;
  state += initstate;
  state = state * MULT + inc;
  for (int i = 0; i < NN; i++)
    for (int j = 0; j < NN; j++) {
      state = state * MULT + inc;
      uint64_t hi = (uint64_t)(state >> 64), lo = (uint64_t)state;
      unsigned rot = (unsigned)(hi >> 58);
      uint64_t xr = hi ^ lo;
      uint64_t out = (xr >> rot) | (xr << ((64u - rot) & 63u));
      double dv = (double)(out >> 11) * (1.0 / 9007199254740992.0);
      adj[i][j] = (dv < 0.25);
    }
}

// ---------------- device ----------------
struct NodeDesc {
  uint8_t node, npred, slot, flags;  // flags bit0: accumulate into acc slot (FINAL)
  uint8_t pred_slot[31];
  uint8_t pad;
};
struct GroupArg { int n; NodeDesc d[16]; };

// Workspace tensors are NHWC: elem(b,y,x,c) = ((b*56+y)*56+x)*64 + c
// 512 threads, ~8 outputs/thread: R6's 256-thread/16-acc shape needed 256
// VGPRs (2 blocks/CU, 11% occ, BW collapsed to 1.34 TB/s). Halving
// per-thread work targets ~100 VGPR -> 3-4 blocks/CU WITHOUT launch-bounds
// minimums (R4/R5: forcing the allocator = scratch spills).
__global__ __launch_bounds__(512) void node_kernel(
    GroupArg g,
    const float* __restrict__ x,
    const float* __restrict__ dwall,
    const float* __restrict__ pwall,
    const float* __restrict__ gmall,
    const float* __restrict__ btall,
    const float* __restrict__ mnall,
    const float* __restrict__ vrall,
    const float* __restrict__ aggw,
    float* __restrict__ ws,
    float* __restrict__ accp)   // FINAL accumulator slot (NHWC)
{
  __shared__ float smem[8192];   // union: halo [100 pos][64 c] (6400) | t (4096) + pw (4096)
  __shared__ float wlds[32];

  const NodeDesc nd = g.d[blockIdx.y];
  const int node = nd.node;
  const int t = threadIdx.x;
  const int b = blockIdx.x / 49;
  const int tile = blockIdx.x - b * 49;
  const int ty = (tile / 7) * 8;
  const int tx = (tile % 7) * 8;

  int dwc, pbase;   // depthwise ownership: channel + first of 8 positions
  if (nd.npred == 0) { dwc = t >> 3; pbase = (t & 7) * 8; }   // NCHW x gather layout
  else               { dwc = t & 63; pbase = (t >> 6) * 8; }  // NHWC halo layout

  const float* k9 = dwall + (node * 64 + dwc) * 9;
  float kk[9];
  #pragma unroll
  for (int q = 0; q < 9; q++) kk[q] = k9[q];

  float tv[8];

  if (nd.npred == 0) {
    // input node: depthwise stride-2 over relu(x), x is NCHW [8][64][112][112]
    const float* xb = x + (size_t)(b * 64 + dwc) * 12544;
    #pragma unroll
    for (int j = 0; j < 8; j++) {
      int p = pbase + j;
      int oy = ty + (p >> 3), ox = tx + (p & 7);
      int iy0 = oy * 2 - 1, ix0 = ox * 2 - 1;
      float s = 0.f;
      #pragma unroll
      for (int dy = 0; dy < 3; dy++) {
        int iy = iy0 + dy;
        if ((unsigned)iy >= 112u) continue;
        const float* row = xb + iy * 112;
        #pragma unroll
        for (int dx = 0; dx < 3; dx++) {
          int ix = ix0 + dx;
          if ((unsigned)ix >= 112u) continue;
          s += fmaxf(row[ix], 0.f) * kk[dy * 3 + dx];
        }
      }
      tv[j] = s;
    }
  } else {
    // sigmoid weights only for >=2 preds (single pred = pass-through)
    if (t < nd.npred) {
      float wv = 1.f / (1.f + expf(-aggw[node * 32 + t]));
      wlds[t] = (nd.npred == 1) ? 1.0f : wv;
    }
    __syncthreads();
    const int np = nd.npred;
    // aggregate + relu into NHWC halo. 1600 float4 units; thread owns 4 units
    // (last only for t<64) -> 4 independent loads in flight per predecessor.
    {
      float4 sa[4];
      bool inb[4];
      long long off[4];
      #pragma unroll
      for (int u = 0; u < 4; u++) {
        int idx = t + u * 512;
        bool valid = (u < 3) || (t < 64);
        int pos = idx >> 4, q = idx & 15;
        int hy = pos / 10, hx = pos - hy * 10;
        int gy = ty + hy - 1, gx = tx + hx - 1;
        inb[u] = valid && ((unsigned)gy < 56u) && ((unsigned)gx < 56u);
        off[u] = ((long long)((b * 56 + gy) * 56 + gx)) * 64 + q * 4;
        sa[u] = make_float4(0.f, 0.f, 0.f, 0.f);
      }
      for (int p = 0; p < np; p++) {
        const float* pb = ws + (size_t)nd.pred_slot[p] * NODE_ELEMS;
        float wv = wlds[p];
        #pragma unroll
        for (int u = 0; u < 4; u++) {
          if (inb[u]) {
            float4 v = *(const float4*)(pb + off[u]);
            sa[u].x += wv * v.x; sa[u].y += wv * v.y;
            sa[u].z += wv * v.z; sa[u].w += wv * v.w;
          }
        }
      }
      #pragma unroll
      for (int u = 0; u < 4; u++) {
        if ((u < 3) || (t < 64)) {
          float4 s = sa[u];
          s.x = fmaxf(s.x, 0.f); s.y = fmaxf(s.y, 0.f);
          s.z = fmaxf(s.z, 0.f); s.w = fmaxf(s.w, 0.f);
          *(float4*)&smem[(t + u * 512) * 4] = s;
        }
      }
    }
    __syncthreads();
    // depthwise 3x3 from NHWC halo: lane = channel -> conflict-free
    #pragma unroll
    for (int j = 0; j < 8; j++) {
      int p = pbase + j;
      int py = p >> 3, px = p & 7;
      const float* r0 = smem + (py * 10 + px) * 64 + dwc;
      tv[j] = r0[0]    * kk[0] + r0[64]   * kk[1] + r0[128]  * kk[2]
            + r0[640]  * kk[3] + r0[704]  * kk[4] + r0[768]  * kk[5]
            + r0[1280] * kk[6] + r0[1344] * kk[7] + r0[1408] * kk[8];
    }
  }

  __syncthreads();  // halo reads done; re-purpose smem

  // t matrix t[p][c] quad-swizzled: quad' = (c>>2) ^ ((p>>2)&15)
  #pragma unroll
  for (int j = 0; j < 8; j++) {
    int p = pbase + j;
    smem[p * 64 + (((((dwc >> 2) ^ ((p >> 2) & 15))) << 2) | (dwc & 3))] = tv[j];
  }
  // pw weights pw[o][c] quad-swizzled: quad' = (c>>2) ^ ((o>>2)&15)
  {
    const float* pwn = pwall + node * 4096;
    #pragma unroll
    for (int i = 0; i < 8; i++) {
      int gidx = t + 512 * i;
      int o = gidx >> 6, cc = gidx & 63;
      smem[4096 + o * 64 + ((((cc >> 2) ^ ((o >> 2) & 15)) << 2) | (cc & 3))] = pwn[gidx];
    }
  }
  __syncthreads();

  // pointwise 64x64: 4 out-channels x 2 positions per thread (8 acc)
  const int oq = t & 15;          // out-channel quad selector
  const int pgrp = t >> 4;        // position pair selector [0,32)
  const int o0 = oq << 2;
  const int p0 = pgrp << 1;
  const int bswz = (pgrp >> 1) & 15;   // (p>>2) for both p0 and p0+1
  float acc[2][4] = {};           // [pj][oi]
  const float* tl = smem;
  const float* pl = smem + 4096;
  #pragma unroll
  for (int k4 = 0; k4 < 16; k4++) {
    float4 A[4], B[2];
    #pragma unroll
    for (int oi = 0; oi < 4; oi++)
      A[oi] = *(const float4*)&pl[(o0 + oi) * 64 + ((k4 ^ oq) << 2)];
    #pragma unroll
    for (int pj = 0; pj < 2; pj++)
      B[pj] = *(const float4*)&tl[(p0 + pj) * 64 + ((k4 ^ bswz) << 2)];
    #pragma unroll
    for (int pj = 0; pj < 2; pj++) {
      #pragma unroll
      for (int oi = 0; oi < 4; oi++) {
        acc[pj][oi] = fmaf(A[oi].x, B[pj].x, acc[pj][oi]);
        acc[pj][oi] = fmaf(A[oi].y, B[pj].y, acc[pj][oi]);
        acc[pj][oi] = fmaf(A[oi].z, B[pj].z, acc[pj][oi]);
        acc[pj][oi] = fmaf(A[oi].w, B[pj].w, acc[pj][oi]);
      }
    }
  }

  // BN + NHWC stores (float4 over out-channels; lanes cover c contiguously)
  float inv[4], mn[4], bt[4];
  #pragma unroll
  for (int oi = 0; oi < 4; oi++) {
    int gi = node * 64 + o0 + oi;
    inv[oi] = gmall[gi] / sqrtf(vrall[gi] + 1e-5f);
    mn[oi] = mnall[gi];
    bt[oi] = btall[gi];
  }
  float* slotp = (nd.slot != 255) ? (ws + (size_t)nd.slot * NODE_ELEMS) : nullptr;
  #pragma unroll
  for (int pj = 0; pj < 2; pj++) {
    int p = p0 + pj;
    int gy = ty + (p >> 3), gx = tx + (p & 7);
    size_t base = (((size_t)(b * 56 + gy)) * 56 + gx) * 64 + o0;
    float o0v = (acc[pj][0] - mn[0]) * inv[0] + bt[0];
    float o1v = (acc[pj][1] - mn[1]) * inv[1] + bt[1];
    float o2v = (acc[pj][2] - mn[2]) * inv[2] + bt[2];
    float o3v = (acc[pj][3] - mn[3]) * inv[3] + bt[3];
    if (slotp) *(float4*)&slotp[base] = make_float4(o0v, o1v, o2v, o3v);
    if (nd.flags & 1) {
      atomicAdd(&accp[base + 0], o0v);
      atomicAdd(&accp[base + 1], o1v);
      atomicAdd(&accp[base + 2], o2v);
      atomicAdd(&accp[base + 3], o3v);
    }
  }
}

// NHWC accumulator -> NCHW d_out, scaled by 1/nf. One block per (b,y) row.
__global__ __launch_bounds__(256) void finalize_kernel(
    const float* __restrict__ accp, float* __restrict__ out, float inv_nf)
{
  __shared__ float lds[57 * 64];
  int by = blockIdx.x;
  int b = by / 56, y = by - b * 56;
  const float* src = accp + (((size_t)b * 56 + y) * 56) * 64;  // [x][c]
  for (int i = threadIdx.x; i < 3584; i += 256) {
    int xx = i >> 6, c = i & 63;
    lds[c * 57 + xx] = src[i] * inv_nf;
  }
  __syncthreads();
  float* dst = out + (size_t)b * 64 * 3136 + y * 56;
  for (int i = threadIdx.x; i < 3584; i += 256) {
    int c = i / 56, xx = i - c * 56;
    dst[(size_t)c * 3136 + xx] = lds[c * 57 + xx];
  }
}

// ---------------- launcher ----------------
extern "C" void kernel_launch(void* const* d_in, const int* in_sizes, int n_in,
                              void* d_out, int out_size, void* d_ws, size_t ws_size,
                              hipStream_t stream) {
  (void)in_sizes; (void)n_in; (void)ws_size; (void)out_size;
  const float* x     = (const float*)d_in[0];
  const float* dw    = (const float*)d_in[1];
  const float* pw    = (const float*)d_in[2];
  const float* gamma = (const float*)d_in[3];
  const float* beta  = (const float*)d_in[4];
  const float* mean  = (const float*)d_in[5];
  const float* var   = (const float*)d_in[6];
  const float* aggw  = (const float*)d_in[7];
  float* ws = (float*)d_ws;
  float* out = (float*)d_out;

  bool adj[NN][NN];
  compute_adj(adj);

  int npred[NN], preds[NN][NN], nsucc[NN], ispan[NN], level[NN];
  for (int j = 0; j < NN; j++) {
    npred[j] = 0;
    for (int i = 0; i < j; i++) if (adj[i][j]) preds[j][npred[j]++] = i;
  }
  for (int i = 0; i < NN; i++) {
    nsucc[i] = 0; ispan[i] = NN;
    int mx = -1;
    for (int j = i + 1; j < NN; j++) if (adj[i][j]) { nsucc[i]++; mx = j; }
    if (nsucc[i] > 0) ispan[i] = mx;
  }
  int maxlev = 0;
  for (int j = 0; j < NN; j++) {
    int lv = 0;
    for (int p = 0; p < npred[j]; p++) {
      int cand = level[preds[j][p]] + 1;
      if (cand > lv) lv = cand;
    }
    level[j] = lv;
    if (lv > maxlev) maxlev = lv;
  }
  bool isfinal[NN]; int nf = 0;
  for (int i = 0; i < NN; i++) { isfinal[i] = (ispan[i] >= NN - 1); if (isfinal[i]) nf++; }
  int lastlvl[NN];
  for (int i = 0; i < NN; i++) {
    lastlvl[i] = -1;
    for (int j = i + 1; j < NN; j++) if (adj[i][j] && level[j] > lastlvl[i]) lastlvl[i] = level[j];
  }
  int slot[NN]; bool used[NN]; int peak = 0;
  for (int s = 0; s < NN; s++) used[s] = false;
  for (int L = 0; L <= maxlev; L++) {
    for (int i = 0; i < NN; i++) {
      if (level[i] != L) continue;
      if (nsucc[i] > 0) {
        int s = 0; while (used[s]) s++;
        used[s] = true; slot[i] = s;
        if (s + 1 > peak) peak = s + 1;
      } else slot[i] = 255;
    }
    for (int i = 0; i < NN; i++)
      if (level[i] < L + 1 && slot[i] != 255 && lastlvl[i] == L && nsucc[i] > 0)
        used[slot[i]] = false;
  }
  int acc_slot = peak;  // one extra slot for the FINAL-mean accumulator
  float* accp = ws + (size_t)acc_slot * NODE_ELEMS;

  hipMemsetAsync(accp, 0, (size_t)NODE_ELEMS * sizeof(float), stream);
  float inv_nf = 1.0f / (float)nf;

  for (int L = 0; L <= maxlev; L++) {
    GroupArg g; g.n = 0;
    for (int i = 0; i < NN; i++) {
      if (level[i] != L) continue;
      NodeDesc& nd = g.d[g.n++];
      nd.node = (uint8_t)i;
      nd.npred = (uint8_t)npred[i];
      nd.slot = (uint8_t)slot[i];
      nd.flags = isfinal[i] ? 1 : 0;
      for (int p = 0; p < npred[i]; p++) nd.pred_slot[p] = (uint8_t)slot[preds[i][p]];
      if (g.n == 16) {
        node_kernel<<<dim3(392, g.n), 512, 0, stream>>>(g, x, dw, pw, gamma, beta,
                                                        mean, var, aggw, ws, accp);
        g.n = 0;
      }
    }
    if (g.n > 0) {
      node_kernel<<<dim3(392, g.n), 512, 0, stream>>>(g, x, dw, pw, gamma, beta,
                                                      mean, var, aggw, ws, accp);
    }
  }
  finalize_kernel<<<448, 256, 0, stream>>>(accp, out, inv_nf);
}

// Round 8
// 1185.140 us; speedup vs baseline: 2.4623x; 2.4623x over previous
//
#include <hip/hip_runtime.h>
#include <cstdint>
#include <cstddef>

#define NN 32
#define NODE_ELEMS 1605632  // 8*56*56*64 (NHWC workspace layout)

typedef unsigned __int128 u128;

// ---------------- host: replicate np.random.default_rng(0).random((32,32)) < 0.25 ----
static void compute_adj(bool adj[NN][NN]) {
  uint32_t pool[4];
  uint32_t hc = 0x43b0d7e5u;
  auto hashmix = [&hc](uint32_t v) -> uint32_t {
    v ^= hc; hc *= 0x931e8875u; v *= hc; v ^= v >> 16; return v;
  };
  auto mix = [](uint32_t x, uint32_t y) -> uint32_t {
    uint32_t r = x * 0xca01f9ddu - y * 0x4973f715u; r ^= r >> 16; return r;
  };
  for (int i = 0; i < 4; i++) pool[i] = hashmix(0u);
  for (int s = 0; s < 4; s++)
    for (int d = 0; d < 4; d++)
      if (s != d) pool[d] = mix(pool[d], hashmix(pool[s]));
  uint32_t hb = 0x8b51f9ddu;
  uint32_t w[8];
  for (int k = 0; k < 8; k++) {
    uint32_t v = pool[k & 3];
    v ^= hb; hb *= 0x58f38dedu; v *= hb; v ^= v >> 16;
    w[k] = v;
  }
  uint64_t s64[4];
  for (int j = 0; j < 4; j++) s64[j] = (uint64_t)w[2 * j] | ((uint64_t)w[2 * j + 1] << 32);
  u128 initstate = ((u128)s64[0] << 64) | s64[1];
  u128 initseq   = ((u128)s64[2] << 64) | s64[3];
  const u128 MULT = ((u128)0x2360ED051FC65DA4ULL << 64) | 0x4385DF649FCCF645ULL;
  u128 state = 0;
  u128 inc = (initseq << 1) | 1;
  state = state * MULT + inc;
  state += initstate;
  state = state * MULT + inc;
  for (int i = 0; i < NN; i++)
    for (int j = 0; j < NN; j++) {
      state = state * MULT + inc;
      uint64_t hi = (uint64_t)(state >> 64), lo = (uint64_t)state;
      unsigned rot = (unsigned)(hi >> 58);
      uint64_t xr = hi ^ lo;
      uint64_t out = (xr >> rot) | (xr << ((64u - rot) & 63u));
      double dv = (double)(out >> 11) * (1.0 / 9007199254740992.0);
      adj[i][j] = (dv < 0.25);
    }
}

// ---------------- device ----------------
struct NodeDesc {
  uint8_t node, npred, slot, flags;  // flags bit0: accumulate into acc slot (FINAL)
  uint8_t pred_slot[31];
  uint8_t pad;
};
struct GroupArg { int n; NodeDesc d[16]; };

// Workspace tensors are NHWC: elem(b,y,x,c) = ((b*56+y)*56+x)*64 + c
// 512 threads. R7 (same shape) spilled at the compiler-chosen VGPR=128
// (+0.9 GB sym. FETCH/WRITE scratch traffic). R8 trims live ranges so 128
// genuinely fits: 2-unit aggregation rounds w/ int offsets, #pragma unroll 4
// on the k4 loop, pw weights staged into a SEPARATE LDS buffer at kernel
// start (overlaps halo-load latency; 42 KB LDS still allows 2 blocks/CU).
__global__ __launch_bounds__(512) void node_kernel(
    GroupArg g,
    const float* __restrict__ x,
    const float* __restrict__ dwall,
    const float* __restrict__ pwall,
    const float* __restrict__ gmall,
    const float* __restrict__ btall,
    const float* __restrict__ mnall,
    const float* __restrict__ vrall,
    const float* __restrict__ aggw,
    float* __restrict__ ws,
    float* __restrict__ accp)   // FINAL accumulator slot (NHWC)
{
  __shared__ float smem[6400];   // halo [100 pos][64 c]; reused as t[64 pos][64 c]
  __shared__ float pwb[4096];    // swizzled pointwise weights
  __shared__ float wlds[32];

  const NodeDesc nd = g.d[blockIdx.y];
  const int node = nd.node;
  const int t = threadIdx.x;
  const int b = blockIdx.x / 49;
  const int tile = blockIdx.x - b * 49;
  const int ty = (tile / 7) * 8;
  const int tx = (tile % 7) * 8;

  // stage pw weights quad-swizzled: (o,c) -> o*64 + (((c>>2)^((o>>2)&15))<<2)|(c&3)
  // issued first so these global loads overlap the aggregation phase
  {
    const float* pwn = pwall + node * 4096;
    #pragma unroll
    for (int i = 0; i < 8; i++) {
      int gidx = t + 512 * i;
      int o = gidx >> 6, cc = gidx & 63;
      pwb[o * 64 + ((((cc >> 2) ^ ((o >> 2) & 15)) << 2) | (cc & 3))] = pwn[gidx];
    }
  }

  int dwc, pbase;   // depthwise ownership: channel + first of 8 positions
  if (nd.npred == 0) { dwc = t >> 3; pbase = (t & 7) * 8; }   // NCHW x gather layout
  else               { dwc = t & 63; pbase = (t >> 6) * 8; }  // NHWC halo layout

  const float* k9 = dwall + (node * 64 + dwc) * 9;
  float kk[9];
  #pragma unroll
  for (int q = 0; q < 9; q++) kk[q] = k9[q];

  float tv[8];

  if (nd.npred == 0) {
    // input node: depthwise stride-2 over relu(x), x is NCHW [8][64][112][112]
    const float* xb = x + (size_t)(b * 64 + dwc) * 12544;
    #pragma unroll
    for (int j = 0; j < 8; j++) {
      int p = pbase + j;
      int oy = ty + (p >> 3), ox = tx + (p & 7);
      int iy0 = oy * 2 - 1, ix0 = ox * 2 - 1;
      float s = 0.f;
      #pragma unroll
      for (int dy = 0; dy < 3; dy++) {
        int iy = iy0 + dy;
        if ((unsigned)iy >= 112u) continue;
        const float* row = xb + iy * 112;
        #pragma unroll
        for (int dx = 0; dx < 3; dx++) {
          int ix = ix0 + dx;
          if ((unsigned)ix >= 112u) continue;
          s += fmaxf(row[ix], 0.f) * kk[dy * 3 + dx];
        }
      }
      tv[j] = s;
    }
    __syncthreads();  // match the else-branch barrier count (wlds)
    __syncthreads();  // (halo build)
    __syncthreads();  // (halo consume)
  } else {
    // sigmoid weights only for >=2 preds (single pred = pass-through)
    if (t < nd.npred) {
      float wv = 1.f / (1.f + expf(-aggw[node * 32 + t]));
      wlds[t] = (nd.npred == 1) ? 1.0f : wv;
    }
    __syncthreads();
    const int np = nd.npred;
    // aggregate + relu into NHWC halo. 1600 float4 units; 2 units per round,
    // 2 rounds -> sa[2]/off[2] live (low reg), 2*np loads in flight.
    #pragma unroll
    for (int r = 0; r < 2; r++) {
      float4 sa[2];
      int off[2];
      bool inb[2];
      #pragma unroll
      for (int u = 0; u < 2; u++) {
        int idx = t + r * 1024 + u * 512;
        bool valid = (r == 0) || (u == 0) || (t < 64);
        int pos = idx >> 4, q = idx & 15;
        int hy = pos / 10, hx = pos - hy * 10;
        int gy = ty + hy - 1, gx = tx + hx - 1;
        inb[u] = valid && ((unsigned)gy < 56u) && ((unsigned)gx < 56u);
        off[u] = ((b * 56 + gy) * 56 + gx) * 64 + q * 4;
        sa[u] = make_float4(0.f, 0.f, 0.f, 0.f);
      }
      for (int p = 0; p < np; p++) {
        const float* pb = ws + (size_t)nd.pred_slot[p] * NODE_ELEMS;
        float wv = wlds[p];
        #pragma unroll
        for (int u = 0; u < 2; u++) {
          if (inb[u]) {
            float4 v = *(const float4*)(pb + off[u]);
            sa[u].x += wv * v.x; sa[u].y += wv * v.y;
            sa[u].z += wv * v.z; sa[u].w += wv * v.w;
          }
        }
      }
      #pragma unroll
      for (int u = 0; u < 2; u++) {
        int idx = t + r * 1024 + u * 512;
        if (idx < 1600) {
          float4 s = sa[u];
          s.x = fmaxf(s.x, 0.f); s.y = fmaxf(s.y, 0.f);
          s.z = fmaxf(s.z, 0.f); s.w = fmaxf(s.w, 0.f);
          *(float4*)&smem[idx * 4] = s;
        }
      }
    }
    __syncthreads();
    // depthwise 3x3 from NHWC halo: lane = channel -> conflict-free
    #pragma unroll
    for (int j = 0; j < 8; j++) {
      int p = pbase + j;
      int py = p >> 3, px = p & 7;
      const float* r0 = smem + (py * 10 + px) * 64 + dwc;
      tv[j] = r0[0]    * kk[0] + r0[64]   * kk[1] + r0[128]  * kk[2]
            + r0[640]  * kk[3] + r0[704]  * kk[4] + r0[768]  * kk[5]
            + r0[1280] * kk[6] + r0[1344] * kk[7] + r0[1408] * kk[8];
    }
    __syncthreads();  // halo reads done; smem re-purposed as t matrix
  }

  // t matrix t[p][c] quad-swizzled: quad' = (c>>2) ^ ((p>>2)&15)
  #pragma unroll
  for (int j = 0; j < 8; j++) {
    int p = pbase + j;
    smem[p * 64 + (((((dwc >> 2) ^ ((p >> 2) & 15))) << 2) | (dwc & 3))] = tv[j];
  }
  __syncthreads();

  // pointwise 64x64: 4 out-channels x 2 positions per thread (8 acc)
  const int oq = t & 15;          // out-channel quad selector
  const int pgrp = t >> 4;        // position pair selector [0,32)
  const int o0 = oq << 2;
  const int p0 = pgrp << 1;
  const int bswz = (pgrp >> 1) & 15;   // (p>>2) for both p0 and p0+1
  float acc[2][4] = {};           // [pj][oi]
  #pragma unroll 4
  for (int k4 = 0; k4 < 16; k4++) {
    float4 A[4], B[2];
    #pragma unroll
    for (int oi = 0; oi < 4; oi++)
      A[oi] = *(const float4*)&pwb[(o0 + oi) * 64 + ((k4 ^ oq) << 2)];
    #pragma unroll
    for (int pj = 0; pj < 2; pj++)
      B[pj] = *(const float4*)&smem[(p0 + pj) * 64 + ((k4 ^ bswz) << 2)];
    #pragma unroll
    for (int pj = 0; pj < 2; pj++) {
      #pragma unroll
      for (int oi = 0; oi < 4; oi++) {
        acc[pj][oi] = fmaf(A[oi].x, B[pj].x, acc[pj][oi]);
        acc[pj][oi] = fmaf(A[oi].y, B[pj].y, acc[pj][oi]);
        acc[pj][oi] = fmaf(A[oi].z, B[pj].z, acc[pj][oi]);
        acc[pj][oi] = fmaf(A[oi].w, B[pj].w, acc[pj][oi]);
      }
    }
  }

  // BN + NHWC stores (float4 over out-channels; lanes cover c contiguously)
  float inv[4], mn[4], bt[4];
  #pragma unroll
  for (int oi = 0; oi < 4; oi++) {
    int gi = node * 64 + o0 + oi;
    inv[oi] = gmall[gi] / sqrtf(vrall[gi] + 1e-5f);
    mn[oi] = mnall[gi];
    bt[oi] = btall[gi];
  }
  float* slotp = (nd.slot != 255) ? (ws + (size_t)nd.slot * NODE_ELEMS) : nullptr;
  #pragma unroll
  for (int pj = 0; pj < 2; pj++) {
    int p = p0 + pj;
    int gy = ty + (p >> 3), gx = tx + (p & 7);
    size_t base = (((size_t)(b * 56 + gy)) * 56 + gx) * 64 + o0;
    float o0v = (acc[pj][0] - mn[0]) * inv[0] + bt[0];
    float o1v = (acc[pj][1] - mn[1]) * inv[1] + bt[1];
    float o2v = (acc[pj][2] - mn[2]) * inv[2] + bt[2];
    float o3v = (acc[pj][3] - mn[3]) * inv[3] + bt[3];
    if (slotp) *(float4*)&slotp[base] = make_float4(o0v, o1v, o2v, o3v);
    if (nd.flags & 1) {
      atomicAdd(&accp[base + 0], o0v);
      atomicAdd(&accp[base + 1], o1v);
      atomicAdd(&accp[base + 2], o2v);
      atomicAdd(&accp[base + 3], o3v);
    }
  }
}

// NHWC accumulator -> NCHW d_out, scaled by 1/nf. One block per (b,y) row.
__global__ __launch_bounds__(256) void finalize_kernel(
    const float* __restrict__ accp, float* __restrict__ out, float inv_nf)
{
  __shared__ float lds[57 * 64];
  int by = blockIdx.x;
  int b = by / 56, y = by - b * 56;
  const float* src = accp + (((size_t)b * 56 + y) * 56) * 64;  // [x][c]
  for (int i = threadIdx.x; i < 3584; i += 256) {
    int xx = i >> 6, c = i & 63;
    lds[c * 57 + xx] = src[i] * inv_nf;
  }
  __syncthreads();
  float* dst = out + (size_t)b * 64 * 3136 + y * 56;
  for (int i = threadIdx.x; i < 3584; i += 256) {
    int c = i / 56, xx = i - c * 56;
    dst[(size_t)c * 3136 + xx] = lds[c * 57 + xx];
  }
}

// ---------------- launcher ----------------
extern "C" void kernel_launch(void* const* d_in, const int* in_sizes, int n_in,
                              void* d_out, int out_size, void* d_ws, size_t ws_size,
                              hipStream_t stream) {
  (void)in_sizes; (void)n_in; (void)ws_size; (void)out_size;
  const float* x     = (const float*)d_in[0];
  const float* dw    = (const float*)d_in[1];
  const float* pw    = (const float*)d_in[2];
  const float* gamma = (const float*)d_in[3];
  const float* beta  = (const float*)d_in[4];
  const float* mean  = (const float*)d_in[5];
  const float* var   = (const float*)d_in[6];
  const float* aggw  = (const float*)d_in[7];
  float* ws = (float*)d_ws;
  float* out = (float*)d_out;

  bool adj[NN][NN];
  compute_adj(adj);

  int npred[NN], preds[NN][NN], nsucc[NN], ispan[NN], level[NN];
  for (int j = 0; j < NN; j++) {
    npred[j] = 0;
    for (int i = 0; i < j; i++) if (adj[i][j]) preds[j][npred[j]++] = i;
  }
  for (int i = 0; i < NN; i++) {
    nsucc[i] = 0; ispan[i] = NN;
    int mx = -1;
    for (int j = i + 1; j < NN; j++) if (adj[i][j]) { nsucc[i]++; mx = j; }
    if (nsucc[i] > 0) ispan[i] = mx;
  }
  int maxlev = 0;
  for (int j = 0; j < NN; j++) {
    int lv = 0;
    for (int p = 0; p < npred[j]; p++) {
      int cand = level[preds[j][p]] + 1;
      if (cand > lv) lv = cand;
    }
    level[j] = lv;
    if (lv > maxlev) maxlev = lv;
  }
  bool isfinal[NN]; int nf = 0;
  for (int i = 0; i < NN; i++) { isfinal[i] = (ispan[i] >= NN - 1); if (isfinal[i]) nf++; }
  int lastlvl[NN];
  for (int i = 0; i < NN; i++) {
    lastlvl[i] = -1;
    for (int j = i + 1; j < NN; j++) if (adj[i][j] && level[j] > lastlvl[i]) lastlvl[i] = level[j];
  }
  int slot[NN]; bool used[NN]; int peak = 0;
  for (int s = 0; s < NN; s++) used[s] = false;
  for (int L = 0; L <= maxlev; L++) {
    for (int i = 0; i < NN; i++) {
      if (level[i] != L) continue;
      if (nsucc[i] > 0) {
        int s = 0; while (used[s]) s++;
        used[s] = true; slot[i] = s;
        if (s + 1 > peak) peak = s + 1;
      } else slot[i] = 255;
    }
    for (int i = 0; i < NN; i++)
      if (level[i] < L + 1 && slot[i] != 255 && lastlvl[i] == L && nsucc[i] > 0)
        used[slot[i]] = false;
  }
  int acc_slot = peak;  // one extra slot for the FINAL-mean accumulator
  float* accp = ws + (size_t)acc_slot * NODE_ELEMS;

  hipMemsetAsync(accp, 0, (size_t)NODE_ELEMS * sizeof(float), stream);
  float inv_nf = 1.0f / (float)nf;

  for (int L = 0; L <= maxlev; L++) {
    GroupArg g; g.n = 0;
    for (int i = 0; i < NN; i++) {
      if (level[i] != L) continue;
      NodeDesc& nd = g.d[g.n++];
      nd.node = (uint8_t)i;
      nd.npred = (uint8_t)npred[i];
      nd.slot = (uint8_t)slot[i];
      nd.flags = isfinal[i] ? 1 : 0;
      for (int p = 0; p < npred[i]; p++) nd.pred_slot[p] = (uint8_t)slot[preds[i][p]];
      if (g.n == 16) {
        node_kernel<<<dim3(392, g.n), 512, 0, stream>>>(g, x, dw, pw, gamma, beta,
                                                        mean, var, aggw, ws, accp);
        g.n = 0;
      }
    }
    if (g.n > 0) {
      node_kernel<<<dim3(392, g.n), 512, 0, stream>>>(g, x, dw, pw, gamma, beta,
                                                      mean, var, aggw, ws, accp);
    }
  }
  finalize_kernel<<<448, 256, 0, stream>>>(accp, out, inv_nf);
}

// Round 9
// 1020.982 us; speedup vs baseline: 2.8582x; 1.1608x over previous
//
#include <hip/hip_runtime.h>
#include <cstdint>
#include <cstddef>

#define NN 32
#define NODE_ELEMS 1605632  // 8*56*56*64 elements per slot (NHWC); bf16 storage

typedef unsigned __int128 u128;

// ---------------- host: replicate np.random.default_rng(0).random((32,32)) < 0.25 ----
static void compute_adj(bool adj[NN][NN]) {
  uint32_t pool[4];
  uint32_t hc = 0x43b0d7e5u;
  auto hashmix = [&hc](uint32_t v) -> uint32_t {
    v ^= hc; hc *= 0x931e8875u; v *= hc; v ^= v >> 16; return v;
  };
  auto mix = [](uint32_t x, uint32_t y) -> uint32_t {
    uint32_t r = x * 0xca01f9ddu - y * 0x4973f715u; r ^= r >> 16; return r;
  };
  for (int i = 0; i < 4; i++) pool[i] = hashmix(0u);
  for (int s = 0; s < 4; s++)
    for (int d = 0; d < 4; d++)
      if (s != d) pool[d] = mix(pool[d], hashmix(pool[s]));
  uint32_t hb = 0x8b51f9ddu;
  uint32_t w[8];
  for (int k = 0; k < 8; k++) {
    uint32_t v = pool[k & 3];
    v ^= hb; hb *= 0x58f38dedu; v *= hb; v ^= v >> 16;
    w[k] = v;
  }
  uint64_t s64[4];
  for (int j = 0; j < 4; j++) s64[j] = (uint64_t)w[2 * j] | ((uint64_t)w[2 * j + 1] << 32);
  u128 initstate = ((u128)s64[0] << 64) | s64[1];
  u128 initseq   = ((u128)s64[2] << 64) | s64[3];
  const u128 MULT = ((u128)0x2360ED051FC65DA4ULL << 64) | 0x4385DF649FCCF645ULL;
  u128 state = 0;
  u128 inc = (initseq << 1) | 1;
  state = state * MULT + inc;
  state += initstate;
  state = state * MULT + inc;
  for (int i = 0; i < NN; i++)
    for (int j = 0; j < NN; j++) {
      state = state * MULT + inc;
      uint64_t hi = (uint64_t)(state >> 64), lo = (uint64_t)state;
      unsigned rot = (unsigned)(hi >> 58);
      uint64_t xr = hi ^ lo;
      uint64_t out = (xr >> rot) | (xr << ((64u - rot) & 63u));
      double dv = (double)(out >> 11) * (1.0 / 9007199254740992.0);
      adj[i][j] = (dv < 0.25);
    }
}

// ---------------- device ----------------
struct NodeDesc {
  uint8_t node, npred, slot, flags;  // flags bit0: accumulate into acc slot (FINAL)
  uint8_t pred_slot[31];
  uint8_t pad;
};
struct GroupArg { int n; NodeDesc d[16]; };

__device__ __forceinline__ float bf2f_lo(unsigned int w) {
  union { unsigned int u; float f; } c; c.u = w << 16; return c.f;
}
__device__ __forceinline__ float bf2f_hi(unsigned int w) {
  union { unsigned int u; float f; } c; c.u = w & 0xFFFF0000u; return c.f;
}
__device__ __forceinline__ unsigned short f2bf(float f) {
  union { float f; unsigned int u; } c; c.f = f;
  unsigned int u = c.u + 0x7FFFu + ((c.u >> 16) & 1u);  // RNE
  return (unsigned short)(u >> 16);
}

// Workspace slots are bf16 NHWC: elem(b,y,x,c) = ((b*56+y)*56+x)*64 + c.
// All math fp32; only inter-node storage is bf16 (halves the dominant
// edge-read traffic: R8 showed heavy dispatches are bytes-bound, VALU 6%).
// 512 threads; R8's live-range discipline kept VGPR=40, zero spill.
__global__ __launch_bounds__(512) void node_kernel(
    GroupArg g,
    const float* __restrict__ x,
    const float* __restrict__ dwall,
    const float* __restrict__ pwall,
    const float* __restrict__ gmall,
    const float* __restrict__ btall,
    const float* __restrict__ mnall,
    const float* __restrict__ vrall,
    const float* __restrict__ aggw,
    unsigned short* __restrict__ wsb,   // bf16 slots
    float* __restrict__ accp)           // FINAL accumulator (fp32 NHWC)
{
  __shared__ float smem[6400];   // halo [100 pos][64 c]; reused as t[64 pos][64 c]
  __shared__ float pwb[4096];    // swizzled pointwise weights
  __shared__ float wlds[32];

  const NodeDesc nd = g.d[blockIdx.y];
  const int node = nd.node;
  const int t = threadIdx.x;
  const int b = blockIdx.x / 49;
  const int tile = blockIdx.x - b * 49;
  const int ty = (tile / 7) * 8;
  const int tx = (tile % 7) * 8;

  // stage pw weights quad-swizzled: (o,c) -> o*64 + (((c>>2)^((o>>2)&15))<<2)|(c&3)
  {
    const float* pwn = pwall + node * 4096;
    #pragma unroll
    for (int i = 0; i < 8; i++) {
      int gidx = t + 512 * i;
      int o = gidx >> 6, cc = gidx & 63;
      pwb[o * 64 + ((((cc >> 2) ^ ((o >> 2) & 15)) << 2) | (cc & 3))] = pwn[gidx];
    }
  }

  int dwc, pbase;   // depthwise ownership: channel + first of 8 positions
  if (nd.npred == 0) { dwc = t >> 3; pbase = (t & 7) * 8; }   // NCHW x gather layout
  else               { dwc = t & 63; pbase = (t >> 6) * 8; }  // NHWC halo layout

  const float* k9 = dwall + (node * 64 + dwc) * 9;
  float kk[9];
  #pragma unroll
  for (int q = 0; q < 9; q++) kk[q] = k9[q];

  float tv[8];

  if (nd.npred == 0) {
    // input node: depthwise stride-2 over relu(x), x is NCHW [8][64][112][112] fp32
    const float* xb = x + (size_t)(b * 64 + dwc) * 12544;
    #pragma unroll
    for (int j = 0; j < 8; j++) {
      int p = pbase + j;
      int oy = ty + (p >> 3), ox = tx + (p & 7);
      int iy0 = oy * 2 - 1, ix0 = ox * 2 - 1;
      float s = 0.f;
      #pragma unroll
      for (int dy = 0; dy < 3; dy++) {
        int iy = iy0 + dy;
        if ((unsigned)iy >= 112u) continue;
        const float* row = xb + iy * 112;
        #pragma unroll
        for (int dx = 0; dx < 3; dx++) {
          int ix = ix0 + dx;
          if ((unsigned)ix >= 112u) continue;
          s += fmaxf(row[ix], 0.f) * kk[dy * 3 + dx];
        }
      }
      tv[j] = s;
    }
    __syncthreads();  // match else-branch barrier count (wlds)
    __syncthreads();  // (halo build)
    __syncthreads();  // (halo consume)
  } else {
    // sigmoid weights only for >=2 preds (single pred = pass-through)
    if (t < nd.npred) {
      float wv = 1.f / (1.f + expf(-aggw[node * 32 + t]));
      wlds[t] = (nd.npred == 1) ? 1.0f : wv;
    }
    __syncthreads();
    const int np = nd.npred;
    // aggregate + relu into fp32 NHWC halo from bf16 slots.
    // 800 units of 8 channels (16 B); thread owns unit t and 512+t (t<288);
    // 2 independent acc chains -> 2*np loads in flight.
    {
      float sa[2][8];
      int off[2];
      bool inb[2];
      #pragma unroll
      for (int u = 0; u < 2; u++) {
        int idx = t + u * 512;
        bool valid = (u == 0) || (t < 288);
        int pos = idx >> 3, q8 = idx & 7;
        int hy = pos / 10, hx = pos - hy * 10;
        int gy = ty + hy - 1, gx = tx + hx - 1;
        inb[u] = valid && ((unsigned)gy < 56u) && ((unsigned)gx < 56u);
        off[u] = ((b * 56 + gy) * 56 + gx) * 64 + q8 * 8;
        #pragma unroll
        for (int k = 0; k < 8; k++) sa[u][k] = 0.f;
      }
      for (int p = 0; p < np; p++) {
        const unsigned short* pb = wsb + (size_t)nd.pred_slot[p] * NODE_ELEMS;
        float wv = wlds[p];
        #pragma unroll
        for (int u = 0; u < 2; u++) {
          if (inb[u]) {
            uint4 v = *(const uint4*)(pb + off[u]);
            sa[u][0] = fmaf(wv, bf2f_lo(v.x), sa[u][0]);
            sa[u][1] = fmaf(wv, bf2f_hi(v.x), sa[u][1]);
            sa[u][2] = fmaf(wv, bf2f_lo(v.y), sa[u][2]);
            sa[u][3] = fmaf(wv, bf2f_hi(v.y), sa[u][3]);
            sa[u][4] = fmaf(wv, bf2f_lo(v.z), sa[u][4]);
            sa[u][5] = fmaf(wv, bf2f_hi(v.z), sa[u][5]);
            sa[u][6] = fmaf(wv, bf2f_lo(v.w), sa[u][6]);
            sa[u][7] = fmaf(wv, bf2f_hi(v.w), sa[u][7]);
          }
        }
      }
      #pragma unroll
      for (int u = 0; u < 2; u++) {
        int idx = t + u * 512;
        if ((u == 0) || (t < 288)) {
          float4 s0 = make_float4(fmaxf(sa[u][0], 0.f), fmaxf(sa[u][1], 0.f),
                                  fmaxf(sa[u][2], 0.f), fmaxf(sa[u][3], 0.f));
          float4 s1 = make_float4(fmaxf(sa[u][4], 0.f), fmaxf(sa[u][5], 0.f),
                                  fmaxf(sa[u][6], 0.f), fmaxf(sa[u][7], 0.f));
          *(float4*)&smem[idx * 8] = s0;
          *(float4*)&smem[idx * 8 + 4] = s1;
        }
      }
    }
    __syncthreads();
    // depthwise 3x3 from NHWC halo: lane = channel -> conflict-free
    #pragma unroll
    for (int j = 0; j < 8; j++) {
      int p = pbase + j;
      int py = p >> 3, px = p & 7;
      const float* r0 = smem + (py * 10 + px) * 64 + dwc;
      tv[j] = r0[0]    * kk[0] + r0[64]   * kk[1] + r0[128]  * kk[2]
            + r0[640]  * kk[3] + r0[704]  * kk[4] + r0[768]  * kk[5]
            + r0[1280] * kk[6] + r0[1344] * kk[7] + r0[1408] * kk[8];
    }
    __syncthreads();  // halo reads done; smem re-purposed as t matrix
  }

  // t matrix t[p][c] quad-swizzled: quad' = (c>>2) ^ ((p>>2)&15)
  #pragma unroll
  for (int j = 0; j < 8; j++) {
    int p = pbase + j;
    smem[p * 64 + (((((dwc >> 2) ^ ((p >> 2) & 15))) << 2) | (dwc & 3))] = tv[j];
  }
  __syncthreads();

  // pointwise 64x64: 4 out-channels x 2 positions per thread (8 acc)
  const int oq = t & 15;          // out-channel quad selector
  const int pgrp = t >> 4;        // position pair selector [0,32)
  const int o0 = oq << 2;
  const int p0 = pgrp << 1;
  const int bswz = (pgrp >> 1) & 15;   // (p>>2) for both p0 and p0+1
  float acc[2][4] = {};           // [pj][oi]
  #pragma unroll 4
  for (int k4 = 0; k4 < 16; k4++) {
    float4 A[4], B[2];
    #pragma unroll
    for (int oi = 0; oi < 4; oi++)
      A[oi] = *(const float4*)&pwb[(o0 + oi) * 64 + ((k4 ^ oq) << 2)];
    #pragma unroll
    for (int pj = 0; pj < 2; pj++)
      B[pj] = *(const float4*)&smem[(p0 + pj) * 64 + ((k4 ^ bswz) << 2)];
    #pragma unroll
    for (int pj = 0; pj < 2; pj++) {
      #pragma unroll
      for (int oi = 0; oi < 4; oi++) {
        acc[pj][oi] = fmaf(A[oi].x, B[pj].x, acc[pj][oi]);
        acc[pj][oi] = fmaf(A[oi].y, B[pj].y, acc[pj][oi]);
        acc[pj][oi] = fmaf(A[oi].z, B[pj].z, acc[pj][oi]);
        acc[pj][oi] = fmaf(A[oi].w, B[pj].w, acc[pj][oi]);
      }
    }
  }

  // BN + stores: slot as bf16 (ushort4 = 8 B), FINAL accumulation fp32 atomics
  float inv[4], mn[4], bt[4];
  #pragma unroll
  for (int oi = 0; oi < 4; oi++) {
    int gi = node * 64 + o0 + oi;
    inv[oi] = gmall[gi] / sqrtf(vrall[gi] + 1e-5f);
    mn[oi] = mnall[gi];
    bt[oi] = btall[gi];
  }
  unsigned short* slotp = (nd.slot != 255) ? (wsb + (size_t)nd.slot * NODE_ELEMS) : nullptr;
  #pragma unroll
  for (int pj = 0; pj < 2; pj++) {
    int p = p0 + pj;
    int gy = ty + (p >> 3), gx = tx + (p & 7);
    size_t base = (((size_t)(b * 56 + gy)) * 56 + gx) * 64 + o0;
    float o0v = (acc[pj][0] - mn[0]) * inv[0] + bt[0];
    float o1v = (acc[pj][1] - mn[1]) * inv[1] + bt[1];
    float o2v = (acc[pj][2] - mn[2]) * inv[2] + bt[2];
    float o3v = (acc[pj][3] - mn[3]) * inv[3] + bt[3];
    if (slotp) {
      ushort4 h;
      h.x = f2bf(o0v); h.y = f2bf(o1v); h.z = f2bf(o2v); h.w = f2bf(o3v);
      *(ushort4*)&slotp[base] = h;
    }
    if (nd.flags & 1) {
      atomicAdd(&accp[base + 0], o0v);
      atomicAdd(&accp[base + 1], o1v);
      atomicAdd(&accp[base + 2], o2v);
      atomicAdd(&accp[base + 3], o3v);
    }
  }
}

// NHWC fp32 accumulator -> NCHW d_out, scaled by 1/nf. One block per (b,y) row.
__global__ __launch_bounds__(256) void finalize_kernel(
    const float* __restrict__ accp, float* __restrict__ out, float inv_nf)
{
  __shared__ float lds[57 * 64];
  int by = blockIdx.x;
  int b = by / 56, y = by - b * 56;
  const float* src = accp + (((size_t)b * 56 + y) * 56) * 64;  // [x][c]
  for (int i = threadIdx.x; i < 3584; i += 256) {
    int xx = i >> 6, c = i & 63;
    lds[c * 57 + xx] = src[i] * inv_nf;
  }
  __syncthreads();
  float* dst = out + (size_t)b * 64 * 3136 + y * 56;
  for (int i = threadIdx.x; i < 3584; i += 256) {
    int c = i / 56, xx = i - c * 56;
    dst[(size_t)c * 3136 + xx] = lds[c * 57 + xx];
  }
}

// ---------------- launcher ----------------
extern "C" void kernel_launch(void* const* d_in, const int* in_sizes, int n_in,
                              void* d_out, int out_size, void* d_ws, size_t ws_size,
                              hipStream_t stream) {
  (void)in_sizes; (void)n_in; (void)ws_size; (void)out_size;
  const float* x     = (const float*)d_in[0];
  const float* dw    = (const float*)d_in[1];
  const float* pw    = (const float*)d_in[2];
  const float* gamma = (const float*)d_in[3];
  const float* beta  = (const float*)d_in[4];
  const float* mean  = (const float*)d_in[5];
  const float* var   = (const float*)d_in[6];
  const float* aggw  = (const float*)d_in[7];
  unsigned short* wsb = (unsigned short*)d_ws;
  float* out = (float*)d_out;

  bool adj[NN][NN];
  compute_adj(adj);

  int npred[NN], preds[NN][NN], nsucc[NN], ispan[NN], level[NN];
  for (int j = 0; j < NN; j++) {
    npred[j] = 0;
    for (int i = 0; i < j; i++) if (adj[i][j]) preds[j][npred[j]++] = i;
  }
  for (int i = 0; i < NN; i++) {
    nsucc[i] = 0; ispan[i] = NN;
    int mx = -1;
    for (int j = i + 1; j < NN; j++) if (adj[i][j]) { nsucc[i]++; mx = j; }
    if (nsucc[i] > 0) ispan[i] = mx;
  }
  int maxlev = 0;
  for (int j = 0; j < NN; j++) {
    int lv = 0;
    for (int p = 0; p < npred[j]; p++) {
      int cand = level[preds[j][p]] + 1;
      if (cand > lv) lv = cand;
    }
    level[j] = lv;
    if (lv > maxlev) maxlev = lv;
  }
  bool isfinal[NN]; int nf = 0;
  for (int i = 0; i < NN; i++) { isfinal[i] = (ispan[i] >= NN - 1); if (isfinal[i]) nf++; }
  int lastlvl[NN];
  for (int i = 0; i < NN; i++) {
    lastlvl[i] = -1;
    for (int j = i + 1; j < NN; j++) if (adj[i][j] && level[j] > lastlvl[i]) lastlvl[i] = level[j];
  }
  int slot[NN]; bool used[NN]; int peak = 0;
  for (int s = 0; s < NN; s++) used[s] = false;
  for (int L = 0; L <= maxlev; L++) {
    for (int i = 0; i < NN; i++) {
      if (level[i] != L) continue;
      if (nsucc[i] > 0) {
        int s = 0; while (used[s]) s++;
        used[s] = true; slot[i] = s;
        if (s + 1 > peak) peak = s + 1;
      } else slot[i] = 255;
    }
    for (int i = 0; i < NN; i++)
      if (level[i] < L + 1 && slot[i] != 255 && lastlvl[i] == L && nsucc[i] > 0)
        used[slot[i]] = false;
  }
  // fp32 FINAL accumulator lives after the bf16 slots
  float* accp = (float*)(wsb + (size_t)peak * NODE_ELEMS);

  hipMemsetAsync(accp, 0, (size_t)NODE_ELEMS * sizeof(float), stream);
  float inv_nf = 1.0f / (float)nf;

  for (int L = 0; L <= maxlev; L++) {
    GroupArg g; g.n = 0;
    for (int i = 0; i < NN; i++) {
      if (level[i] != L) continue;
      NodeDesc& nd = g.d[g.n++];
      nd.node = (uint8_t)i;
      nd.npred = (uint8_t)npred[i];
      nd.slot = (uint8_t)slot[i];
      nd.flags = isfinal[i] ? 1 : 0;
      for (int p = 0; p < npred[i]; p++) nd.pred_slot[p] = (uint8_t)slot[preds[i][p]];
      if (g.n == 16) {
        node_kernel<<<dim3(392, g.n), 512, 0, stream>>>(g, x, dw, pw, gamma, beta,
                                                        mean, var, aggw, wsb, accp);
        g.n = 0;
      }
    }
    if (g.n > 0) {
      node_kernel<<<dim3(392, g.n), 512, 0, stream>>>(g, x, dw, pw, gamma, beta,
                                                      mean, var, aggw, wsb, accp);
    }
  }
  finalize_kernel<<<448, 256, 0, stream>>>(accp, out, inv_nf);
}